// Round 1
// baseline (289.905 us; speedup 1.0000x reference)
//
#include <hip/hip_runtime.h>
#include <hip/hip_bf16.h>

// SurfaceLoss: 16x256x256 grid through 3->128->128->128->1 tanh MLP, MSE vs images.
// Layers 2/3 as bf16 MFMA (16x16x32), layer 1 + loss in fp32.

#define BATCH 16
#define YS 256
#define XS 256
#define HDIM 128
#define LDA 136                 // padded LDS row stride (bf16 elems), pad=8 -> 2-way (free) banks
#define STEP (256.0f / 255.0f)  // linspace(-128,128,256) step

typedef __bf16 v8bf __attribute__((ext_vector_type(8)));
typedef float  v4f  __attribute__((ext_vector_type(4)));

__device__ __forceinline__ unsigned short f2bf(float f) {
    unsigned int u = __float_as_uint(f);
    unsigned int r = (u + 0x7fffu + ((u >> 16) & 1u)) >> 16;
    return (unsigned short)r;
}

__device__ __forceinline__ float tanh_fast(float z) {
    // tanh(z) = 1 - 2/(exp(2z)+1); clamp so exp2 can't overflow
    float zc = __builtin_amdgcn_fmed3f(z, -15.f, 15.f);
    float e  = __builtin_amdgcn_exp2f(zc * 2.885390081777927f);  // exp(2z) = 2^(2z*log2e)
    float r  = __builtin_amdgcn_rcpf(e + 1.f);
    return 1.f - 2.f * r;
}

// ---- prep: transpose W2, W3 (128x128 fp32, row-major [k][n]) to bf16 [n][k] ----
__global__ __launch_bounds__(256) void prep_kernel(
    const float* __restrict__ W2, const float* __restrict__ W3,
    unsigned short* __restrict__ w2t, unsigned short* __restrict__ w3t)
{
    const float* src = blockIdx.x ? W3 : W2;
    unsigned short* dst = blockIdx.x ? w3t : w2t;
    const int tid = threadIdx.x;
    #pragma unroll
    for (int i = 0; i < 64; ++i) {
        int e = i * 256 + tid;
        int n = e >> 7, k = e & 127;
        dst[e] = f2bf(src[k * 128 + n]);   // dst[n*128+k] = W[k][n]
    }
}

// ---- main: one block = 128 consecutive pixels of one image row ----
__global__ __launch_bounds__(256) void main_kernel(
    const float* __restrict__ images,
    const float* __restrict__ W1, const float* __restrict__ b1,
    const float* __restrict__ b2, const float* __restrict__ b3,
    const float* __restrict__ W4, const float* __restrict__ b4,
    const int*   __restrict__ np,
    const unsigned short* __restrict__ w2t,
    const unsigned short* __restrict__ w3t,
    float* __restrict__ partials)
{
    __shared__ unsigned short A[128 * LDA];   // activation tile, bf16, padded

    const int tid  = threadIdx.x;
    const int lane = tid & 63;
    const int w    = tid >> 6;        // wave id 0..3
    const int l15  = lane & 15;
    const int quad = lane >> 4;

    const int bid = blockIdx.x;
    const int b   = bid >> 9;          // 512 blocks per batch image
    const int rem = bid & 511;
    const int r   = rem >> 1;          // image row (x index)
    const int c0  = (rem & 1) << 7;    // column tile base (y index base)

    const float tv = (float)(b + np[0] * BATCH);
    const float xv = -128.f + (float)r * STEP;

    // ---- W2 B-fragments straight from global (L2-hot), [n][k] layout ----
    v8bf w2f[2][4];
    #pragma unroll
    for (int nt = 0; nt < 2; ++nt) {
        int row = w * 32 + nt * 16 + l15;
        #pragma unroll
        for (int ks = 0; ks < 4; ++ks)
            w2f[nt][ks] = *(const v8bf*)(w2t + row * 128 + ks * 32 + quad * 8);
    }

    // ---- layer 1 (fp32): h1 = tanh(xv*W1x + yv*W1y + tv*W1t + b1) -> A ----
    {
        const int lo = tid & 15, hi = tid >> 4;
        const int j0 = lo * 8, p0 = hi * 8;
        float wx[8], wy[8], wt[8], bb[8], cj[8];
        *(float4*)&wx[0] = *(const float4*)(W1 + j0);
        *(float4*)&wx[4] = *(const float4*)(W1 + j0 + 4);
        *(float4*)&wy[0] = *(const float4*)(W1 + 128 + j0);
        *(float4*)&wy[4] = *(const float4*)(W1 + 128 + j0 + 4);
        *(float4*)&wt[0] = *(const float4*)(W1 + 256 + j0);
        *(float4*)&wt[4] = *(const float4*)(W1 + 256 + j0 + 4);
        *(float4*)&bb[0] = *(const float4*)(b1 + j0);
        *(float4*)&bb[4] = *(const float4*)(b1 + j0 + 4);
        #pragma unroll
        for (int l = 0; l < 8; ++l)
            cj[l] = fmaf(xv, wx[l], fmaf(tv, wt[l], bb[l]));
        #pragma unroll
        for (int pi = 0; pi < 8; ++pi) {
            const int p = p0 + pi;
            const float yv = -128.f + (float)(c0 + p) * STEP;
            unsigned int pk[4];
            #pragma unroll
            for (int l = 0; l < 4; ++l) {
                float h0 = tanh_fast(fmaf(yv, wy[2 * l],     cj[2 * l]));
                float h1 = tanh_fast(fmaf(yv, wy[2 * l + 1], cj[2 * l + 1]));
                pk[l] = (unsigned)f2bf(h0) | ((unsigned)f2bf(h1) << 16);
            }
            *(uint4*)&A[p * LDA + j0] = make_uint4(pk[0], pk[1], pk[2], pk[3]);
        }
    }
    __syncthreads();

    // ---- layer 2 MFMA: C(128x128) = A @ W2 ----
    v4f acc[8][2];
    #pragma unroll
    for (int mt = 0; mt < 8; ++mt) {
        acc[mt][0] = (v4f){0.f, 0.f, 0.f, 0.f};
        acc[mt][1] = (v4f){0.f, 0.f, 0.f, 0.f};
    }
    #pragma unroll
    for (int ks = 0; ks < 4; ++ks) {
        #pragma unroll
        for (int mt = 0; mt < 8; ++mt) {
            v8bf af = *(const v8bf*)&A[(mt * 16 + l15) * LDA + ks * 32 + quad * 8];
            acc[mt][0] = __builtin_amdgcn_mfma_f32_16x16x32_bf16(af, w2f[0][ks], acc[mt][0], 0, 0, 0);
            acc[mt][1] = __builtin_amdgcn_mfma_f32_16x16x32_bf16(af, w2f[1][ks], acc[mt][1], 0, 0, 0);
        }
    }

    // prefetch W3 fragments while acc epilogue pending
    v8bf w3f[2][4];
    #pragma unroll
    for (int nt = 0; nt < 2; ++nt) {
        int row = w * 32 + nt * 16 + l15;
        #pragma unroll
        for (int ks = 0; ks < 4; ++ks)
            w3f[nt][ks] = *(const v8bf*)(w3t + row * 128 + ks * 32 + quad * 8);
    }
    __syncthreads();   // all waves done reading A for layer 2

    // ---- epilogue 2: tanh(acc + b2) -> A ----
    {
        float bi0 = b2[w * 32 + l15], bi1 = b2[w * 32 + 16 + l15];
        #pragma unroll
        for (int mt = 0; mt < 8; ++mt) {
            #pragma unroll
            for (int nt = 0; nt < 2; ++nt) {
                float bias = nt ? bi1 : bi0;
                #pragma unroll
                for (int rg = 0; rg < 4; ++rg) {
                    float h = tanh_fast(acc[mt][nt][rg] + bias);
                    A[(mt * 16 + quad * 4 + rg) * LDA + (w * 32 + nt * 16 + l15)] = f2bf(h);
                }
            }
        }
    }
    __syncthreads();

    // ---- layer 3 MFMA ----
    #pragma unroll
    for (int mt = 0; mt < 8; ++mt) {
        acc[mt][0] = (v4f){0.f, 0.f, 0.f, 0.f};
        acc[mt][1] = (v4f){0.f, 0.f, 0.f, 0.f};
    }
    #pragma unroll
    for (int ks = 0; ks < 4; ++ks) {
        #pragma unroll
        for (int mt = 0; mt < 8; ++mt) {
            v8bf af = *(const v8bf*)&A[(mt * 16 + l15) * LDA + ks * 32 + quad * 8];
            acc[mt][0] = __builtin_amdgcn_mfma_f32_16x16x32_bf16(af, w3f[0][ks], acc[mt][0], 0, 0, 0);
            acc[mt][1] = __builtin_amdgcn_mfma_f32_16x16x32_bf16(af, w3f[1][ks], acc[mt][1], 0, 0, 0);
        }
    }
    __syncthreads();   // all waves done reading A for layer 3

    // ---- epilogue 3: tanh(acc + b3) -> A ----
    {
        float bi0 = b3[w * 32 + l15], bi1 = b3[w * 32 + 16 + l15];
        #pragma unroll
        for (int mt = 0; mt < 8; ++mt) {
            #pragma unroll
            for (int nt = 0; nt < 2; ++nt) {
                float bias = nt ? bi1 : bi0;
                #pragma unroll
                for (int rg = 0; rg < 4; ++rg) {
                    float h = tanh_fast(acc[mt][nt][rg] + bias);
                    A[(mt * 16 + quad * 4 + rg) * LDA + (w * 32 + nt * 16 + l15)] = f2bf(h);
                }
            }
        }
    }
    __syncthreads();

    // ---- layer 4 + loss: recon = h3 . W4 + b4 ; accumulate (img-recon)^2 ----
    {
        const int p  = tid >> 1;           // 2 threads per point
        const int jb = (tid & 1) * 64;
        float s = 0.f;
        #pragma unroll
        for (int g = 0; g < 8; ++g) {
            uint4 u = *(const uint4*)&A[p * LDA + jb + g * 8];
            float4 wa = *(const float4*)(W4 + jb + g * 8);
            float4 wb = *(const float4*)(W4 + jb + g * 8 + 4);
            s += __uint_as_float(u.x << 16)          * wa.x;
            s += __uint_as_float(u.x & 0xffff0000u)  * wa.y;
            s += __uint_as_float(u.y << 16)          * wa.z;
            s += __uint_as_float(u.y & 0xffff0000u)  * wa.w;
            s += __uint_as_float(u.z << 16)          * wb.x;
            s += __uint_as_float(u.z & 0xffff0000u)  * wb.y;
            s += __uint_as_float(u.w << 16)          * wb.z;
            s += __uint_as_float(u.w & 0xffff0000u)  * wb.w;
        }
        s += __shfl_xor(s, 1, 64);        // combine the two half-dots
        float e2 = 0.f;
        if ((tid & 1) == 0) {
            float recon = s + b4[0];
            float img = images[(b << 16) + (r << 8) + c0 + p];
            float err = img - recon;
            e2 = err * err;
        }
        #pragma unroll
        for (int off = 1; off < 64; off <<= 1)
            e2 += __shfl_xor(e2, off, 64);
        if (lane == 0)
            atomicAdd(&partials[bid & 1023], e2);
    }
}

// ---- finish: reduce 1024 partials, scale by 1/(B*YS*XS) ----
__global__ __launch_bounds__(256) void finish_kernel(
    const float* __restrict__ partials, float* __restrict__ out)
{
    const int tid = threadIdx.x;
    float s = partials[tid] + partials[tid + 256] + partials[tid + 512] + partials[tid + 768];
    #pragma unroll
    for (int off = 1; off < 64; off <<= 1)
        s += __shfl_xor(s, off, 64);
    __shared__ float red[4];
    if ((tid & 63) == 0) red[tid >> 6] = s;
    __syncthreads();
    if (tid == 0)
        out[0] = (red[0] + red[1] + red[2] + red[3]) * (1.f / 1048576.f);
}

extern "C" void kernel_launch(void* const* d_in, const int* in_sizes, int n_in,
                              void* d_out, int out_size, void* d_ws, size_t ws_size,
                              hipStream_t stream)
{
    const float* images = (const float*)d_in[0];
    const float* W1 = (const float*)d_in[1];
    const float* b1 = (const float*)d_in[2];
    const float* W2 = (const float*)d_in[3];
    const float* b2 = (const float*)d_in[4];
    const float* W3 = (const float*)d_in[5];
    const float* b3 = (const float*)d_in[6];
    const float* W4 = (const float*)d_in[7];
    const float* b4 = (const float*)d_in[8];
    const int*   np = (const int*)d_in[10];

    unsigned short* w2t = (unsigned short*)d_ws;            // 32 KB
    unsigned short* w3t = w2t + 128 * 128;                  // 32 KB
    float* partials = (float*)((char*)d_ws + 65536);        // 4 KB

    hipMemsetAsync(partials, 0, 1024 * sizeof(float), stream);
    prep_kernel<<<2, 256, 0, stream>>>(W2, W3, w2t, w3t);
    main_kernel<<<BATCH * YS * (XS / 128), 256, 0, stream>>>(
        images, W1, b1, b2, b3, W4, b4, np, w2t, w3t, partials);
    finish_kernel<<<1, 256, 0, stream>>>(partials, (float*)d_out);
}

// Round 2
// 236.271 us; speedup vs baseline: 1.2270x; 1.2270x over previous
//
#include <hip/hip_runtime.h>
#include <hip/hip_bf16.h>

// SurfaceLoss: 16x256x256 grid through 3->128->128->128->1 tanh MLP, MSE vs images.
// Layers 2/3 bf16 MFMA (16x16x32), layer 1 + loss fp32.
// R2: pre-scale weights by 2*log2(e) (exp2-direct tanh, no clamp/mul),
//     v_cvt_pk_bf16_f32 packing, 512-thread blocks for 32 waves/CU.

#define BATCH 16
#define LDA 136                 // padded LDS row stride (bf16 elems), pad=8 -> conflict-free b128 reads
#define STEP (256.0f / 255.0f)  // linspace(-128,128,256) step
#define KS 2.8853900817779268f  // 2*log2(e): tanh(z) = 1 - 2/(exp2(KS*z)+1)

typedef __bf16 v8bf __attribute__((ext_vector_type(8)));
typedef float  v4f  __attribute__((ext_vector_type(4)));

__device__ __forceinline__ unsigned short f2bf(float f) {
    unsigned int u = __float_as_uint(f);
    unsigned int r = (u + 0x7fffu + ((u >> 16) & 1u)) >> 16;
    return (unsigned short)r;
}

#if __has_builtin(__builtin_amdgcn_cvt_pk_bf16_f32)
__device__ __forceinline__ unsigned int pack2bf(float a, float b) {
    auto p = __builtin_amdgcn_cvt_pk_bf16_f32(a, b);   // lo=a, hi=b
    union { decltype(p) v; unsigned int u; } c; c.v = p;
    return c.u;
}
#else
__device__ __forceinline__ unsigned int pack2bf(float a, float b) {
    return (unsigned)f2bf(a) | ((unsigned)f2bf(b) << 16);
}
#endif

// input already scaled by KS; exact at +/-inf ends, no NaN possible for finite z
__device__ __forceinline__ float tanh_pre(float zk) {
    float e = __builtin_amdgcn_exp2f(zk);
    float r = __builtin_amdgcn_rcpf(e + 1.f);
    return fmaf(-2.f, r, 1.f);
}

// ---- prep: W2,W3 (128x128 fp32 [k][n]) -> bf16 [n][k], pre-scaled by KS ----
__global__ __launch_bounds__(256) void prep_kernel(
    const float* __restrict__ W2, const float* __restrict__ W3,
    unsigned short* __restrict__ w2t, unsigned short* __restrict__ w3t)
{
    int o = blockIdx.x * 256 + threadIdx.x;    // grid 128 -> 32768 elems
    const float* src = (o < 16384) ? W2 : W3;
    unsigned short* dst = (o < 16384) ? w2t : w3t;
    int e = o & 16383;
    int k = e >> 7, n = e & 127;
    dst[n * 128 + k] = f2bf(src[e] * KS);      // coalesced read, scattered b16 write (L2)
}

// ---- main: one block (512 thr, 8 waves) = 128 consecutive pixels of one image row ----
__global__ __launch_bounds__(512, 8) void main_kernel(
    const float* __restrict__ images,
    const float* __restrict__ W1, const float* __restrict__ b1,
    const float* __restrict__ b2, const float* __restrict__ b3,
    const float* __restrict__ W4, const float* __restrict__ b4,
    const int*   __restrict__ np,
    const unsigned short* __restrict__ w2t,
    const unsigned short* __restrict__ w3t,
    float* __restrict__ partials)
{
    __shared__ unsigned short A[128 * LDA];

    const int tid  = threadIdx.x;
    const int lane = tid & 63;
    const int w    = tid >> 6;        // wave 0..7, owns 16 output cols
    const int l15  = lane & 15;
    const int quad = lane >> 4;

    const int bid = blockIdx.x;
    const int b   = bid >> 9;          // 512 blocks per image
    const int rem = bid & 511;
    const int r   = rem >> 1;          // image row (x index)
    const int c0  = (rem & 1) << 7;    // y base

    const float tv = (float)(b + np[0] * BATCH);
    const float xv = -128.f + (float)r * STEP;

    // ---- layer 1 (fp32, pre-scaled by KS): each thread 4 cols x 8 points ----
    {
        const int lo = tid & 31, hi = tid >> 5;
        const int j0 = lo * 4, p0 = hi * 8;
        float4 wx = *(const float4*)(W1 + j0);
        float4 wy = *(const float4*)(W1 + 128 + j0);
        float4 wt = *(const float4*)(W1 + 256 + j0);
        float4 bb = *(const float4*)(b1 + j0);
        float cj0 = KS * fmaf(xv, wx.x, fmaf(tv, wt.x, bb.x));
        float cj1 = KS * fmaf(xv, wx.y, fmaf(tv, wt.y, bb.y));
        float cj2 = KS * fmaf(xv, wx.z, fmaf(tv, wt.z, bb.z));
        float cj3 = KS * fmaf(xv, wx.w, fmaf(tv, wt.w, bb.w));
        float wy0 = KS * wy.x, wy1 = KS * wy.y, wy2 = KS * wy.z, wy3 = KS * wy.w;
        #pragma unroll
        for (int pi = 0; pi < 8; ++pi) {
            const int p = p0 + pi;
            const float yv = fmaf((float)(c0 + p), STEP, -128.f);
            float t0 = tanh_pre(fmaf(yv, wy0, cj0));
            float t1 = tanh_pre(fmaf(yv, wy1, cj1));
            float t2 = tanh_pre(fmaf(yv, wy2, cj2));
            float t3 = tanh_pre(fmaf(yv, wy3, cj3));
            uint2 u = make_uint2(pack2bf(t0, t1), pack2bf(t2, t3));
            *(uint2*)&A[p * LDA + j0] = u;   // 8B store, conflict-free
        }
    }
    __syncthreads();

    const int colw = w * 16 + l15;     // this lane's output column

    // ---- W2 B-fragments from L2 ([n][k] layout, pre-scaled) ----
    v8bf wf[4];
    #pragma unroll
    for (int ks = 0; ks < 4; ++ks)
        wf[ks] = *(const v8bf*)(w2t + colw * 128 + ks * 32 + quad * 8);

    // ---- layer 2 MFMA ----
    v4f acc[8];
    #pragma unroll
    for (int mt = 0; mt < 8; ++mt) acc[mt] = (v4f){0.f, 0.f, 0.f, 0.f};
    #pragma unroll
    for (int ks = 0; ks < 4; ++ks) {
        #pragma unroll
        for (int mt = 0; mt < 8; ++mt) {
            v8bf af = *(const v8bf*)&A[(mt * 16 + l15) * LDA + ks * 32 + quad * 8];
            acc[mt] = __builtin_amdgcn_mfma_f32_16x16x32_bf16(af, wf[ks], acc[mt], 0, 0, 0);
        }
    }

    // prefetch W3 fragments (reuses wf slots after last use via regalloc)
    v8bf w3f[4];
    #pragma unroll
    for (int ks = 0; ks < 4; ++ks)
        w3f[ks] = *(const v8bf*)(w3t + colw * 128 + ks * 32 + quad * 8);
    __syncthreads();   // all waves done reading A

    // ---- epilogue 2: tanh(acc + KS*b2) -> A (acc already KS-scaled) ----
    {
        float biK = b2[colw] * KS;
        #pragma unroll
        for (int mt = 0; mt < 8; ++mt) {
            float t0 = tanh_pre(acc[mt][0] + biK);
            float t1 = tanh_pre(acc[mt][1] + biK);
            float t2 = tanh_pre(acc[mt][2] + biK);
            float t3 = tanh_pre(acc[mt][3] + biK);
            unsigned u01 = pack2bf(t0, t1);
            unsigned u23 = pack2bf(t2, t3);
            int rowb = (mt * 16 + quad * 4) * LDA + colw;
            A[rowb]           = (unsigned short)u01;
            A[rowb + LDA]     = (unsigned short)(u01 >> 16);
            A[rowb + 2 * LDA] = (unsigned short)u23;
            A[rowb + 3 * LDA] = (unsigned short)(u23 >> 16);
        }
    }
    __syncthreads();

    // ---- layer 3 MFMA ----
    #pragma unroll
    for (int mt = 0; mt < 8; ++mt) acc[mt] = (v4f){0.f, 0.f, 0.f, 0.f};
    #pragma unroll
    for (int ks = 0; ks < 4; ++ks) {
        #pragma unroll
        for (int mt = 0; mt < 8; ++mt) {
            v8bf af = *(const v8bf*)&A[(mt * 16 + l15) * LDA + ks * 32 + quad * 8];
            acc[mt] = __builtin_amdgcn_mfma_f32_16x16x32_bf16(af, w3f[ks], acc[mt], 0, 0, 0);
        }
    }
    __syncthreads();

    // ---- epilogue 3: plain tanh out (unscaled h3) ----
    {
        float biK = b3[colw] * KS;
        #pragma unroll
        for (int mt = 0; mt < 8; ++mt) {
            float t0 = tanh_pre(acc[mt][0] + biK);
            float t1 = tanh_pre(acc[mt][1] + biK);
            float t2 = tanh_pre(acc[mt][2] + biK);
            float t3 = tanh_pre(acc[mt][3] + biK);
            unsigned u01 = pack2bf(t0, t1);
            unsigned u23 = pack2bf(t2, t3);
            int rowb = (mt * 16 + quad * 4) * LDA + colw;
            A[rowb]           = (unsigned short)u01;
            A[rowb + LDA]     = (unsigned short)(u01 >> 16);
            A[rowb + 2 * LDA] = (unsigned short)u23;
            A[rowb + 3 * LDA] = (unsigned short)(u23 >> 16);
        }
    }
    __syncthreads();

    // ---- layer 4 + loss: 4 threads per point, 32 terms each ----
    {
        const int p  = tid >> 2;
        const int jb = (tid & 3) * 32;
        float s = 0.f;
        #pragma unroll
        for (int g = 0; g < 4; ++g) {
            uint4 u = *(const uint4*)&A[p * LDA + jb + g * 8];
            float4 wa = *(const float4*)(W4 + jb + g * 8);
            float4 wb = *(const float4*)(W4 + jb + g * 8 + 4);
            s += __uint_as_float(u.x << 16)          * wa.x;
            s += __uint_as_float(u.x & 0xffff0000u)  * wa.y;
            s += __uint_as_float(u.y << 16)          * wa.z;
            s += __uint_as_float(u.y & 0xffff0000u)  * wa.w;
            s += __uint_as_float(u.z << 16)          * wb.x;
            s += __uint_as_float(u.z & 0xffff0000u)  * wb.y;
            s += __uint_as_float(u.w << 16)          * wb.z;
            s += __uint_as_float(u.w & 0xffff0000u)  * wb.w;
        }
        s += __shfl_xor(s, 1, 64);
        s += __shfl_xor(s, 2, 64);
        float e2 = 0.f;
        if ((tid & 3) == 0) {
            float recon = s + b4[0];
            float img = images[(b << 16) + (r << 8) + c0 + p];
            float err = img - recon;
            e2 = err * err;
        }
        #pragma unroll
        for (int off = 4; off < 64; off <<= 1)
            e2 += __shfl_xor(e2, off, 64);
        if (lane == 0)
            atomicAdd(&partials[bid & 1023], e2);
    }
}

// ---- finish: reduce 1024 partials, scale by 1/(B*YS*XS) ----
__global__ __launch_bounds__(256) void finish_kernel(
    const float* __restrict__ partials, float* __restrict__ out)
{
    const int tid = threadIdx.x;
    float s = partials[tid] + partials[tid + 256] + partials[tid + 512] + partials[tid + 768];
    #pragma unroll
    for (int off = 1; off < 64; off <<= 1)
        s += __shfl_xor(s, off, 64);
    __shared__ float red[4];
    if ((tid & 63) == 0) red[tid >> 6] = s;
    __syncthreads();
    if (tid == 0)
        out[0] = (red[0] + red[1] + red[2] + red[3]) * (1.f / 1048576.f);
}

extern "C" void kernel_launch(void* const* d_in, const int* in_sizes, int n_in,
                              void* d_out, int out_size, void* d_ws, size_t ws_size,
                              hipStream_t stream)
{
    const float* images = (const float*)d_in[0];
    const float* W1 = (const float*)d_in[1];
    const float* b1 = (const float*)d_in[2];
    const float* W2 = (const float*)d_in[3];
    const float* b2 = (const float*)d_in[4];
    const float* W3 = (const float*)d_in[5];
    const float* b3 = (const float*)d_in[6];
    const float* W4 = (const float*)d_in[7];
    const float* b4 = (const float*)d_in[8];
    const int*   np = (const int*)d_in[10];

    unsigned short* w2t = (unsigned short*)d_ws;            // 32 KB
    unsigned short* w3t = w2t + 128 * 128;                  // 32 KB
    float* partials = (float*)((char*)d_ws + 65536);        // 4 KB

    hipMemsetAsync(partials, 0, 1024 * sizeof(float), stream);
    prep_kernel<<<128, 256, 0, stream>>>(W2, W3, w2t, w3t);
    main_kernel<<<BATCH * 256 * 2, 512, 0, stream>>>(
        images, W1, b1, b2, b3, W4, b4, np, w2t, w3t, partials);
    finish_kernel<<<1, 256, 0, stream>>>(partials, (float*)d_out);
}